// Round 7
// baseline (198.880 us; speedup 1.0000x reference)
//
#include <hip/hip_runtime.h>
#include <math.h>

#define N    24
#define D    256
#define BLK  256
#define NB   4            // batches per block = waves per block
#define CTS  33           // costT row stride: 33 % 32 == 1 -> conflict-free column reads
#define INFV 1e9f

__device__ __forceinline__ int readlane_i(int x, int l) {
    return __builtin_amdgcn_readlane(x, l);
}
__device__ __forceinline__ float readlane_f(float x, int l) {
    return __uint_as_float((unsigned)__builtin_amdgcn_readlane((int)__float_as_uint(x), l));
}

// unsigned-min reduce over lanes 0..31 (lanes 32..63 must hold large keys);
// result valid in lane 31. Pure DPP/VALU — no DS pipe.
__device__ __forceinline__ unsigned wave_min32(unsigned x) {
    unsigned t;
    t = (unsigned)__builtin_amdgcn_update_dpp((int)x, (int)x, 0xB1,  0xF, 0xF, false); x = t < x ? t : x; // quad_perm [1,0,3,2]
    t = (unsigned)__builtin_amdgcn_update_dpp((int)x, (int)x, 0x4E,  0xF, 0xF, false); x = t < x ? t : x; // quad_perm [2,3,0,1]
    t = (unsigned)__builtin_amdgcn_update_dpp((int)x, (int)x, 0x114, 0xF, 0xF, false); x = t < x ? t : x; // row_shr:4
    t = (unsigned)__builtin_amdgcn_update_dpp((int)x, (int)x, 0x118, 0xF, 0xF, false); x = t < x ? t : x; // row_shr:8  -> lane15 = row min
    t = (unsigned)__builtin_amdgcn_update_dpp((int)x, (int)x, 0x142, 0xF, 0xF, false); x = t < x ? t : x; // row_bcast:15 -> lane31 = min(0..31)
    return x;
}

// Branchless 24-way register select for wave-uniform i0: 23 v_cndmask, depth 5.
// Retested under the predicated R6 loop structure (R1's test was confounded).
__device__ __forceinline__ float sel24(const float* cq, int i0) {
    const bool b0 = (i0 & 1) != 0, b1 = (i0 & 2) != 0, b2 = (i0 & 4) != 0;
    float t0 = b0 ? cq[1]  : cq[0];
    float t1 = b0 ? cq[3]  : cq[2];
    float t2 = b0 ? cq[5]  : cq[4];
    float t3 = b0 ? cq[7]  : cq[6];
    float t4 = b0 ? cq[9]  : cq[8];
    float t5 = b0 ? cq[11] : cq[10];
    float t6 = b0 ? cq[13] : cq[12];
    float t7 = b0 ? cq[15] : cq[14];
    float t8 = b0 ? cq[17] : cq[16];
    float t9 = b0 ? cq[19] : cq[18];
    float tA = b0 ? cq[21] : cq[20];
    float tB = b0 ? cq[23] : cq[22];
    float u0 = b1 ? t1 : t0;
    float u1 = b1 ? t3 : t2;
    float u2 = b1 ? t5 : t4;
    float u3 = b1 ? t7 : t6;
    float u4 = b1 ? t9 : t8;
    float u5 = b1 ? tB : tA;
    float w0 = b2 ? u1 : u0;   // rows 0..7
    float w1 = b2 ? u3 : u2;   // rows 8..15
    float w2 = b2 ? u5 : u4;   // rows 16..23
    const bool g1 = (i0 & 8) != 0, g2 = (i0 & 16) != 0;
    float x = g1 ? w1 : w0;
    return g2 ? w2 : x;
}

__device__ __forceinline__ unsigned packkey(float x, int lane) {
    unsigned key = __float_as_uint(x);
    key ^= (unsigned)((int)key >> 31) | 0x80000000u;
    return (key & 0xFFFFFFC0u) | (unsigned)lane;
}

#define DOT4(a, b) ((a).x*(b).x + (a).y*(b).y + (a).z*(b).z + (a).w*(b).w)
#define LGKM0() __asm__ volatile("s_waitcnt lgkmcnt(0)" ::: "memory")

__global__ __launch_bounds__(BLK) void hungarian_fused(
    const float* __restrict__ slots,
    const float* __restrict__ prev,
    float* __restrict__ out, int B)
{
    __shared__ float costT[NB][N][CTS];               // [wave][col][row]
    __shared__ int winner[NB][N];                     // col claiming row r
    __shared__ int colw[NB][N];                       // col_ind[row]

    const int tid  = threadIdx.x;
    const int lane = tid & 63;
    const int wv   = tid >> 6;
    const int bw   = blockIdx.x * NB + wv;
    if (bw >= B) return;

    // ============ Phase A: per-wave cost GEMM straight from global =========
    const int rg = lane >> 3;       // prev rows 3rg..3rg+2
    const int cg = lane & 7;        // cur  rows 3cg..3cg+2
    const float4* pA = (const float4*)(prev  + (size_t)bw * N * D) + rg * 3 * (D / 4);
    const float4* pC = (const float4*)(slots + (size_t)bw * N * D) + cg * 3 * (D / 4);

    float s00=0,s01=0,s02=0,s10=0,s11=0,s12=0,s20=0,s21=0,s22=0;
    float pa0=0,pa1=0,pa2=0,pc0=0,pc1=0,pc2=0;
    #pragma unroll 2
    for (int k = 0; k < 64; ++k) {
        float4 a0 = pA[k], a1 = pA[64+k], a2 = pA[128+k];
        float4 b0 = pC[k], b1 = pC[64+k], b2 = pC[128+k];
        s00 += DOT4(a0,b0); s01 += DOT4(a0,b1); s02 += DOT4(a0,b2);
        s10 += DOT4(a1,b0); s11 += DOT4(a1,b1); s12 += DOT4(a1,b2);
        s20 += DOT4(a2,b0); s21 += DOT4(a2,b1); s22 += DOT4(a2,b2);
        pa0 += DOT4(a0,a0); pa1 += DOT4(a1,a1); pa2 += DOT4(a2,a2);
        pc0 += DOT4(b0,b0); pc1 += DOT4(b1,b1); pc2 += DOT4(b2,b2);
    }
    float ira0 = 1.0f / fmaxf(sqrtf(pa0), 1e-12f);
    float ira1 = 1.0f / fmaxf(sqrtf(pa1), 1e-12f);
    float ira2 = 1.0f / fmaxf(sqrtf(pa2), 1e-12f);
    float irc0 = 1.0f / fmaxf(sqrtf(pc0), 1e-12f);
    float irc1 = 1.0f / fmaxf(sqrtf(pc1), 1e-12f);
    float irc2 = 1.0f / fmaxf(sqrtf(pc2), 1e-12f);

    {   // costT[col][row] = 1 - <prev_row, cur_col> * ira * irc
        float* ct = &costT[wv][0][0];
        const int cb = cg * 3, rb = rg * 3;
        ct[(cb+0)*CTS + rb+0] = 1.0f - s00*ira0*irc0;
        ct[(cb+1)*CTS + rb+0] = 1.0f - s01*ira0*irc1;
        ct[(cb+2)*CTS + rb+0] = 1.0f - s02*ira0*irc2;
        ct[(cb+0)*CTS + rb+1] = 1.0f - s10*ira1*irc0;
        ct[(cb+1)*CTS + rb+1] = 1.0f - s11*ira1*irc1;
        ct[(cb+2)*CTS + rb+1] = 1.0f - s12*ira1*irc2;
        ct[(cb+0)*CTS + rb+2] = 1.0f - s20*ira2*irc0;
        ct[(cb+1)*CTS + rb+2] = 1.0f - s21*ira2*irc1;
        ct[(cb+2)*CTS + rb+2] = 1.0f - s22*ira2*irc2;
    }
    LGKM0();   // order ds_write -> ds_read within this wave

    // ============ Phase B: Hungarian (JV SAP), one wave/batch ==============
    // Lane j owns column j. Fully predicated loop body; cost column held in
    // registers (cq), selected by a cndmask tree — no LDS, no branches.
    const bool isCol = (lane < N);
    const int  cl    = isCol ? lane : (N - 1);   // lanes>=24: broadcast col 23
    const float* __restrict__ ctcol = &costT[wv][cl][0];  // stride 33: conflict-free

    // ---- cost column into registers + column-reduction warm start ----
    float cq[N];
    #pragma unroll
    for (int i = 0; i < N; ++i) cq[i] = ctcol[i];
    float cm = cq[0]; int ri = 0;
    #pragma unroll
    for (int i = 1; i < N; ++i) { if (cq[i] < cm) { cm = cq[i]; ri = i; } }

    if (isCol) winner[wv][lane] = -1;
    LGKM0();
    if (isCol) winner[wv][ri] = lane;     // races resolve to one winner
    LGKM0();
    int p = -1;                           // row assigned to col `lane`
    if (isCol && winner[wv][ri] == lane) p = ri;
    const int widx = isCol ? lane : 0;
    unsigned long long mm = __ballot(isCol && winner[wv][widx] >= 0);
    unsigned freeRows = (~(unsigned)mm) & ((1u << N) - 1);

    float uu  = 0.0f;                     // lane r: row potential u[r]
    float pu  = 0.0f;                     // lane j: u[p[j]] shadow (exact; u==0 now)
    float v   = isCol ? cm : INFV;        // lane j: col potential v[j]
    int   way = -1;                       // lane j: parent col on path

    while (freeRows) {
        const int f = (int)__builtin_ctz(freeRows);
        freeRows &= freeRows - 1;

        float minv  = INFV;
        bool  used  = !isCol;             // lanes>=24 permanently excluded
        bool  inTree = false;
        int   s_j0 = -1;                  // virtual column
        int   s_i0 = f;
        float s_u0 = readlane_f(uu, f);
        int   j1   = 0;

        while (true) {
            inTree = inTree || (lane == s_i0);

            // C[s_i0][lane]: register cndmask tree (uniform s_i0)
            float cij = sel24(cq, s_i0);
            float cur = (cij - s_u0) - v;             // exact old association

            bool imp = (!used) && (cur < minv);
            minv = imp ? cur : minv;                  // used lanes frozen at INFV
            way  = imp ? s_j0 : way;

            // packed argmin via DPP: monotone uint key, low 6 bits = lane
            unsigned kmin = (unsigned)readlane_i(
                (int)wave_min32(packkey(minv, lane)), 31);
            j1 = (int)(kmin & 63u);

            // three INDEPENDENT readlanes off j1 (pu shadow kills the
            // old p[j1] -> uu[p[j1]] serialized double-hop)
            float delta = readlane_f(minv, j1);
            int   i0n   = readlane_i(p, j1);
            float u0n   = readlane_f(pu, j1);

            // dual updates — predicated, same used/inTree sets as before
            uu   = inTree ? uu + delta : uu;
            v    = used   ? v - delta  : v;
            pu   = used   ? pu + delta : pu;          // mirrors u[p[j]]
            minv = used   ? minv       : minv - delta;

            // col j1 joins the used set for subsequent iterations
            bool sel = (lane == j1);
            minv = sel ? INFV : minv;
            used = used || sel;

            if (i0n < 0) break;                       // free column reached
            s_j0 = j1; s_i0 = i0n; s_u0 = u0n;
        }

        // augment back to the virtual column; resync pu = u[p[j]] on the path
        int jcur = j1;
        while (true) {
            int   wj   = readlane_i(way, jcur);
            int   pnew = (wj < 0) ? f : readlane_i(p, wj);
            float pun  = readlane_f(uu, pnew);
            if (lane == jcur) { p = pnew; pu = pun; }
            if (wj < 0) break;
            jcur = wj;
        }
    }

    if (isCol) colw[wv][p] = lane;        // col_ind[row p] = col `lane`
    LGKM0();

    // ============ Phase C: gather out[i][:] = slots[col[i]][:] =============
    const float4* sg4 = (const float4*)(slots + (size_t)bw * N * D);
    float4*       og4 = (float4*)(out + (size_t)bw * N * D);
    #pragma unroll
    for (int i = 0; i < N; ++i) {
        int c = colw[wv][i];
        og4[i * 64 + lane] = sg4[c * 64 + lane];
    }
}

extern "C" void kernel_launch(void* const* d_in, const int* in_sizes, int n_in,
                              void* d_out, int out_size, void* d_ws, size_t ws_size,
                              hipStream_t stream) {
    const float* slots = (const float*)d_in[0];
    const float* prev  = (const float*)d_in[1];
    float* out = (float*)d_out;
    int B = in_sizes[0] / (N * D);
    int grid = (B + NB - 1) / NB;
    hungarian_fused<<<grid, BLK, 0, stream>>>(slots, prev, out, B);
}

// Round 9
// 193.852 us; speedup vs baseline: 1.0259x; 1.0259x over previous
//
#include <hip/hip_runtime.h>
#include <math.h>

#define N    24
#define D    256
#define BLK  256
#define NB   4            // batches per block = waves per block
#define CTS  33           // costT row stride: 33 % 32 == 1 -> conflict-free column reads
#define INFV 1e9f

__device__ __forceinline__ int readlane_i(int x, int l) {
    return __builtin_amdgcn_readlane(x, l);
}
__device__ __forceinline__ float readlane_f(float x, int l) {
    return __uint_as_float((unsigned)__builtin_amdgcn_readlane((int)__float_as_uint(x), l));
}

// unsigned-min reduce over lanes 0..31 (lanes 32..63 must hold large keys);
// result valid in lane 31. Pure DPP/VALU — no DS pipe.
__device__ __forceinline__ unsigned wave_min32(unsigned x) {
    unsigned t;
    t = (unsigned)__builtin_amdgcn_update_dpp((int)x, (int)x, 0xB1,  0xF, 0xF, false); x = t < x ? t : x; // quad_perm [1,0,3,2]
    t = (unsigned)__builtin_amdgcn_update_dpp((int)x, (int)x, 0x4E,  0xF, 0xF, false); x = t < x ? t : x; // quad_perm [2,3,0,1]
    t = (unsigned)__builtin_amdgcn_update_dpp((int)x, (int)x, 0x114, 0xF, 0xF, false); x = t < x ? t : x; // row_shr:4
    t = (unsigned)__builtin_amdgcn_update_dpp((int)x, (int)x, 0x118, 0xF, 0xF, false); x = t < x ? t : x; // row_shr:8  -> lane15 = row min
    t = (unsigned)__builtin_amdgcn_update_dpp((int)x, (int)x, 0x142, 0xF, 0xF, false); x = t < x ? t : x; // row_bcast:15 -> lane31 = min(0..31)
    return x;
}

__device__ __forceinline__ unsigned packkey(float x, int lane) {
    unsigned key = __float_as_uint(x);
    key ^= (unsigned)((int)key >> 31) | 0x80000000u;
    return (key & 0xFFFFFFC0u) | (unsigned)lane;
}

// Branchless 24-way select over NAMED scalars (no array, no address-taken —
// spill-proof; R1/R7's array version spilled to scratch: WRITE_SIZE 49152->61440).
// 23 v_cndmask, depth 5, masks precomputed from uniform bits via SALU.
#define SEL24(I) ({                                                        \
    const int  _i  = (I);                                                  \
    const bool _b0 = (_i & 1)  != 0, _b1 = (_i & 2)  != 0,                 \
               _b2 = (_i & 4)  != 0, _g1 = (_i & 8)  != 0,                 \
               _g2 = (_i & 16) != 0;                                       \
    float _t0 = _b0 ? c01 : c00;  float _t1 = _b0 ? c03 : c02;             \
    float _t2 = _b0 ? c05 : c04;  float _t3 = _b0 ? c07 : c06;             \
    float _t4 = _b0 ? c09 : c08;  float _t5 = _b0 ? c11 : c10;             \
    float _t6 = _b0 ? c13 : c12;  float _t7 = _b0 ? c15 : c14;             \
    float _t8 = _b0 ? c17 : c16;  float _t9 = _b0 ? c19 : c18;             \
    float _tA = _b0 ? c21 : c20;  float _tB = _b0 ? c23 : c22;             \
    float _u0 = _b1 ? _t1 : _t0;  float _u1 = _b1 ? _t3 : _t2;             \
    float _u2 = _b1 ? _t5 : _t4;  float _u3 = _b1 ? _t7 : _t6;             \
    float _u4 = _b1 ? _t9 : _t8;  float _u5 = _b1 ? _tB : _tA;             \
    float _w0 = _b2 ? _u1 : _u0;  float _w1 = _b2 ? _u3 : _u2;             \
    float _w2 = _b2 ? _u5 : _u4;                                           \
    float _x  = _g1 ? _w1 : _w0;                                           \
    _g2 ? _w2 : _x; })

#define DOT4(a, b) ((a).x*(b).x + (a).y*(b).y + (a).z*(b).z + (a).w*(b).w)
#define LGKM0() __asm__ volatile("s_waitcnt lgkmcnt(0)" ::: "memory")

__global__ __launch_bounds__(BLK) void hungarian_fused(
    const float* __restrict__ slots,
    const float* __restrict__ prev,
    float* __restrict__ out, int B)
{
    __shared__ float costT[NB][N][CTS];               // [wave][col][row]
    __shared__ int winner[NB][N];                     // col claiming row r
    __shared__ int colw[NB][N];                       // col_ind[row]

    const int tid  = threadIdx.x;
    const int lane = tid & 63;
    const int wv   = tid >> 6;
    const int bw   = blockIdx.x * NB + wv;
    if (bw >= B) return;

    // ============ Phase A: per-wave cost GEMM straight from global =========
    const int rg = lane >> 3;       // prev rows 3rg..3rg+2
    const int cg = lane & 7;        // cur  rows 3cg..3cg+2
    const float4* pA = (const float4*)(prev  + (size_t)bw * N * D) + rg * 3 * (D / 4);
    const float4* pC = (const float4*)(slots + (size_t)bw * N * D) + cg * 3 * (D / 4);

    float s00=0,s01=0,s02=0,s10=0,s11=0,s12=0,s20=0,s21=0,s22=0;
    float pa0=0,pa1=0,pa2=0,pc0=0,pc1=0,pc2=0;
    #pragma unroll 2
    for (int k = 0; k < 64; ++k) {
        float4 a0 = pA[k], a1 = pA[64+k], a2 = pA[128+k];
        float4 b0 = pC[k], b1 = pC[64+k], b2 = pC[128+k];
        s00 += DOT4(a0,b0); s01 += DOT4(a0,b1); s02 += DOT4(a0,b2);
        s10 += DOT4(a1,b0); s11 += DOT4(a1,b1); s12 += DOT4(a1,b2);
        s20 += DOT4(a2,b0); s21 += DOT4(a2,b1); s22 += DOT4(a2,b2);
        pa0 += DOT4(a0,a0); pa1 += DOT4(a1,a1); pa2 += DOT4(a2,a2);
        pc0 += DOT4(b0,b0); pc1 += DOT4(b1,b1); pc2 += DOT4(b2,b2);
    }
    float ira0 = 1.0f / fmaxf(sqrtf(pa0), 1e-12f);
    float ira1 = 1.0f / fmaxf(sqrtf(pa1), 1e-12f);
    float ira2 = 1.0f / fmaxf(sqrtf(pa2), 1e-12f);
    float irc0 = 1.0f / fmaxf(sqrtf(pc0), 1e-12f);
    float irc1 = 1.0f / fmaxf(sqrtf(pc1), 1e-12f);
    float irc2 = 1.0f / fmaxf(sqrtf(pc2), 1e-12f);

    {   // costT[col][row] = 1 - <prev_row, cur_col> * ira * irc
        float* ct = &costT[wv][0][0];
        const int cb = cg * 3, rb = rg * 3;
        ct[(cb+0)*CTS + rb+0] = 1.0f - s00*ira0*irc0;
        ct[(cb+1)*CTS + rb+0] = 1.0f - s01*ira0*irc1;
        ct[(cb+2)*CTS + rb+0] = 1.0f - s02*ira0*irc2;
        ct[(cb+0)*CTS + rb+1] = 1.0f - s10*ira1*irc0;
        ct[(cb+1)*CTS + rb+1] = 1.0f - s11*ira1*irc1;
        ct[(cb+2)*CTS + rb+1] = 1.0f - s12*ira1*irc2;
        ct[(cb+0)*CTS + rb+2] = 1.0f - s20*ira2*irc0;
        ct[(cb+1)*CTS + rb+2] = 1.0f - s21*ira2*irc1;
        ct[(cb+2)*CTS + rb+2] = 1.0f - s22*ira2*irc2;
    }
    LGKM0();   // order ds_write -> ds_read within this wave

    // ============ Phase B: Hungarian (JV SAP), one wave/batch ==============
    // Lane j owns column j. Fully predicated loop body; cost column held in
    // 24 NAMED registers; select-ahead overlaps the tree with dual updates.
    const bool isCol = (lane < N);
    const int  cl    = isCol ? lane : (N - 1);   // lanes>=24: broadcast col 23
    const float* __restrict__ ctcol = &costT[wv][cl][0];  // stride 33: conflict-free

    float c00 = ctcol[0],  c01 = ctcol[1],  c02 = ctcol[2],  c03 = ctcol[3];
    float c04 = ctcol[4],  c05 = ctcol[5],  c06 = ctcol[6],  c07 = ctcol[7];
    float c08 = ctcol[8],  c09 = ctcol[9],  c10 = ctcol[10], c11 = ctcol[11];
    float c12 = ctcol[12], c13 = ctcol[13], c14 = ctcol[14], c15 = ctcol[15];
    float c16 = ctcol[16], c17 = ctcol[17], c18 = ctcol[18], c19 = ctcol[19];
    float c20 = ctcol[20], c21 = ctcol[21], c22 = ctcol[22], c23 = ctcol[23];

    // ---- column reduction warm start: v[j] = min_i C[i][j] ----
    float cm = c00; int ri = 0;
    if (c01 < cm) { cm = c01; ri = 1;  }   if (c02 < cm) { cm = c02; ri = 2;  }
    if (c03 < cm) { cm = c03; ri = 3;  }   if (c04 < cm) { cm = c04; ri = 4;  }
    if (c05 < cm) { cm = c05; ri = 5;  }   if (c06 < cm) { cm = c06; ri = 6;  }
    if (c07 < cm) { cm = c07; ri = 7;  }   if (c08 < cm) { cm = c08; ri = 8;  }
    if (c09 < cm) { cm = c09; ri = 9;  }   if (c10 < cm) { cm = c10; ri = 10; }
    if (c11 < cm) { cm = c11; ri = 11; }   if (c12 < cm) { cm = c12; ri = 12; }
    if (c13 < cm) { cm = c13; ri = 13; }   if (c14 < cm) { cm = c14; ri = 14; }
    if (c15 < cm) { cm = c15; ri = 15; }   if (c16 < cm) { cm = c16; ri = 16; }
    if (c17 < cm) { cm = c17; ri = 17; }   if (c18 < cm) { cm = c18; ri = 18; }
    if (c19 < cm) { cm = c19; ri = 19; }   if (c20 < cm) { cm = c20; ri = 20; }
    if (c21 < cm) { cm = c21; ri = 21; }   if (c22 < cm) { cm = c22; ri = 22; }
    if (c23 < cm) { cm = c23; ri = 23; }

    if (isCol) winner[wv][lane] = -1;
    LGKM0();
    if (isCol) winner[wv][ri] = lane;     // races resolve to one winner
    LGKM0();
    int p = -1;                           // row assigned to col `lane`
    if (isCol && winner[wv][ri] == lane) p = ri;
    const int widx = isCol ? lane : 0;
    unsigned long long mm = __ballot(isCol && winner[wv][widx] >= 0);
    unsigned freeRows = (~(unsigned)mm) & ((1u << N) - 1);

    float uu  = 0.0f;                     // lane r: row potential u[r]
    float pu  = 0.0f;                     // lane j: u[p[j]] shadow (exact; u==0 now)
    float v   = isCol ? cm : INFV;        // lane j: col potential v[j]
    int   way = -1;                       // lane j: parent col on path

    while (freeRows) {
        const int f = (int)__builtin_ctz(freeRows);
        freeRows &= freeRows - 1;

        float minv  = INFV;
        bool  used  = !isCol;             // lanes>=24 permanently excluded
        bool  inTree = false;
        int   s_j0 = -1;                  // virtual column
        int   s_i0 = f;
        float s_u0 = readlane_f(uu, f);
        float cij  = SEL24(s_i0);         // head select hoisted out of loop
        int   j1   = 0;

        while (true) {
            inTree = inTree || (lane == s_i0);

            float cur = (cij - s_u0) - v;             // exact old association

            bool imp = (!used) && (cur < minv);
            minv = imp ? cur : minv;                  // used lanes frozen at INFV
            way  = imp ? s_j0 : way;

            // packed argmin via DPP: monotone uint key, low 6 bits = lane
            unsigned kmin = (unsigned)readlane_i(
                (int)wave_min32(packkey(minv, lane)), 31);
            j1 = (int)(kmin & 63u);

            // three INDEPENDENT readlanes off j1
            float delta = readlane_f(minv, j1);
            int   i0n   = readlane_i(p, j1);
            float u0n   = readlane_f(pu, j1);

            // select-ahead: next row's costs, overlaps the update block
            // (i0n==-1 -> all bits set -> harmlessly selects c23; break below)
            float cijN = SEL24(i0n);

            // dual updates — predicated, same used/inTree sets as before
            uu   = inTree ? uu + delta : uu;
            v    = used   ? v - delta  : v;
            pu   = used   ? pu + delta : pu;          // mirrors u[p[j]]
            minv = used   ? minv       : minv - delta;

            // col j1 joins the used set for subsequent iterations
            bool sel = (lane == j1);
            minv = sel ? INFV : minv;
            used = used || sel;

            if (i0n < 0) break;                       // free column reached
            s_j0 = j1; s_i0 = i0n; s_u0 = u0n; cij = cijN;
        }

        // augment back to the virtual column; resync pu = u[p[j]] on the path
        int jcur = j1;
        while (true) {
            int   wj   = readlane_i(way, jcur);
            int   pnew = (wj < 0) ? f : readlane_i(p, wj);
            float pun  = readlane_f(uu, pnew);
            if (lane == jcur) { p = pnew; pu = pun; }
            if (wj < 0) break;
            jcur = wj;
        }
    }

    if (isCol) colw[wv][p] = lane;        // col_ind[row p] = col `lane`
    LGKM0();

    // ============ Phase C: gather out[i][:] = slots[col[i]][:] =============
    const float4* sg4 = (const float4*)(slots + (size_t)bw * N * D);
    float4*       og4 = (float4*)(out + (size_t)bw * N * D);
    #pragma unroll
    for (int i = 0; i < N; ++i) {
        int c = colw[wv][i];
        og4[i * 64 + lane] = sg4[c * 64 + lane];
    }
}

extern "C" void kernel_launch(void* const* d_in, const int* in_sizes, int n_in,
                              void* d_out, int out_size, void* d_ws, size_t ws_size,
                              hipStream_t stream) {
    const float* slots = (const float*)d_in[0];
    const float* prev  = (const float*)d_in[1];
    float* out = (float*)d_out;
    int B = in_sizes[0] / (N * D);
    int grid = (B + NB - 1) / NB;
    hungarian_fused<<<grid, BLK, 0, stream>>>(slots, prev, out, B);
}

// Round 10
// 186.561 us; speedup vs baseline: 1.0660x; 1.0391x over previous
//
#include <hip/hip_runtime.h>
#include <math.h>

#define N    24
#define D    256
#define BLK  256
#define NB   4            // batches per block = waves per block
#define CTS  33           // costT row stride: 33 % 32 == 1 -> conflict-free column reads
#define INFV 1e9f

__device__ __forceinline__ int readlane_i(int x, int l) {
    return __builtin_amdgcn_readlane(x, l);
}
__device__ __forceinline__ float readlane_f(float x, int l) {
    return __uint_as_float((unsigned)__builtin_amdgcn_readlane((int)__float_as_uint(x), l));
}

// unsigned-min reduce over lanes 0..31 (lanes 32..63 must hold large keys);
// result valid in lane 31. Pure DPP/VALU — no DS pipe.
__device__ __forceinline__ unsigned wave_min32(unsigned x) {
    unsigned t;
    t = (unsigned)__builtin_amdgcn_update_dpp((int)x, (int)x, 0xB1,  0xF, 0xF, false); x = t < x ? t : x; // quad_perm [1,0,3,2]
    t = (unsigned)__builtin_amdgcn_update_dpp((int)x, (int)x, 0x4E,  0xF, 0xF, false); x = t < x ? t : x; // quad_perm [2,3,0,1]
    t = (unsigned)__builtin_amdgcn_update_dpp((int)x, (int)x, 0x114, 0xF, 0xF, false); x = t < x ? t : x; // row_shr:4
    t = (unsigned)__builtin_amdgcn_update_dpp((int)x, (int)x, 0x118, 0xF, 0xF, false); x = t < x ? t : x; // row_shr:8  -> lane15 = row min
    t = (unsigned)__builtin_amdgcn_update_dpp((int)x, (int)x, 0x142, 0xF, 0xF, false); x = t < x ? t : x; // row_bcast:15 -> lane31 = min(0..31)
    return x;
}

__device__ __forceinline__ unsigned packkey(float x, int lane) {
    unsigned key = __float_as_uint(x);
    key ^= (unsigned)((int)key >> 31) | 0x80000000u;
    return (key & 0xFFFFFFC0u) | (unsigned)lane;
}

#define DOT4(a, b) ((a).x*(b).x + (a).y*(b).y + (a).z*(b).z + (a).w*(b).w)
#define LGKM0() __asm__ volatile("s_waitcnt lgkmcnt(0)" ::: "memory")

__global__ __launch_bounds__(BLK) void hungarian_fused(
    const float* __restrict__ slots,
    const float* __restrict__ prev,
    float* __restrict__ out, int B)
{
    __shared__ float costT[NB][N][CTS];               // [wave][col][row]
    __shared__ int winner[NB][N];                     // col claiming row r
    __shared__ int colw[NB][N];                       // col_ind[row]

    const int tid  = threadIdx.x;
    const int lane = tid & 63;
    const int wv   = tid >> 6;
    const int bw   = blockIdx.x * NB + wv;
    if (bw >= B) return;

    // ============ Phase A: per-wave cost GEMM straight from global =========
    const int rg = lane >> 3;       // prev rows 3rg..3rg+2
    const int cg = lane & 7;        // cur  rows 3cg..3cg+2
    const float4* pA = (const float4*)(prev  + (size_t)bw * N * D) + rg * 3 * (D / 4);
    const float4* pC = (const float4*)(slots + (size_t)bw * N * D) + cg * 3 * (D / 4);

    float s00=0,s01=0,s02=0,s10=0,s11=0,s12=0,s20=0,s21=0,s22=0;
    float pa0=0,pa1=0,pa2=0,pc0=0,pc1=0,pc2=0;
    #pragma unroll 2
    for (int k = 0; k < 64; ++k) {
        float4 a0 = pA[k], a1 = pA[64+k], a2 = pA[128+k];
        float4 b0 = pC[k], b1 = pC[64+k], b2 = pC[128+k];
        s00 += DOT4(a0,b0); s01 += DOT4(a0,b1); s02 += DOT4(a0,b2);
        s10 += DOT4(a1,b0); s11 += DOT4(a1,b1); s12 += DOT4(a1,b2);
        s20 += DOT4(a2,b0); s21 += DOT4(a2,b1); s22 += DOT4(a2,b2);
        pa0 += DOT4(a0,a0); pa1 += DOT4(a1,a1); pa2 += DOT4(a2,a2);
        pc0 += DOT4(b0,b0); pc1 += DOT4(b1,b1); pc2 += DOT4(b2,b2);
    }
    float ira0 = 1.0f / fmaxf(sqrtf(pa0), 1e-12f);
    float ira1 = 1.0f / fmaxf(sqrtf(pa1), 1e-12f);
    float ira2 = 1.0f / fmaxf(sqrtf(pa2), 1e-12f);
    float irc0 = 1.0f / fmaxf(sqrtf(pc0), 1e-12f);
    float irc1 = 1.0f / fmaxf(sqrtf(pc1), 1e-12f);
    float irc2 = 1.0f / fmaxf(sqrtf(pc2), 1e-12f);

    {   // costT[col][row] = 1 - <prev_row, cur_col> * ira * irc
        float* ct = &costT[wv][0][0];
        const int cb = cg * 3, rb = rg * 3;
        ct[(cb+0)*CTS + rb+0] = 1.0f - s00*ira0*irc0;
        ct[(cb+1)*CTS + rb+0] = 1.0f - s01*ira0*irc1;
        ct[(cb+2)*CTS + rb+0] = 1.0f - s02*ira0*irc2;
        ct[(cb+0)*CTS + rb+1] = 1.0f - s10*ira1*irc0;
        ct[(cb+1)*CTS + rb+1] = 1.0f - s11*ira1*irc1;
        ct[(cb+2)*CTS + rb+1] = 1.0f - s12*ira1*irc2;
        ct[(cb+0)*CTS + rb+2] = 1.0f - s20*ira2*irc0;
        ct[(cb+1)*CTS + rb+2] = 1.0f - s21*ira2*irc1;
        ct[(cb+2)*CTS + rb+2] = 1.0f - s22*ira2*irc2;
    }
    LGKM0();   // order ds_write -> ds_read within this wave

    // ============ Phase B: Hungarian (JV SAP), one wave/batch ==============
    // Lane j owns column j. Fully predicated loop body (R6 structure);
    // next-row cost ds_read issued at loop BOTTOM so its latency hides
    // under the dual-update block and backedge.
    const bool isCol = (lane < N);
    const int  cl    = isCol ? lane : (N - 1);   // lanes>=24: broadcast col 23
    const float* __restrict__ ctcol = &costT[wv][cl][0];  // stride 33: conflict-free

    // ---- column reduction warm start: v[j] = min_i C[i][j] ----
    float cq[N];
    #pragma unroll
    for (int i = 0; i < N; ++i) cq[i] = ctcol[i];
    float cm = cq[0]; int ri = 0;
    #pragma unroll
    for (int i = 1; i < N; ++i) { if (cq[i] < cm) { cm = cq[i]; ri = i; } }

    if (isCol) winner[wv][lane] = -1;
    LGKM0();
    if (isCol) winner[wv][ri] = lane;     // races resolve to one winner
    LGKM0();
    int p = -1;                           // row assigned to col `lane`
    if (isCol && winner[wv][ri] == lane) p = ri;
    const int widx = isCol ? lane : 0;
    unsigned long long mm = __ballot(isCol && winner[wv][widx] >= 0);
    unsigned freeRows = (~(unsigned)mm) & ((1u << N) - 1);

    float uu  = 0.0f;                     // lane r: row potential u[r]
    float pu  = 0.0f;                     // lane j: u[p[j]] shadow (exact; u==0 now)
    float v   = isCol ? cm : INFV;        // lane j: col potential v[j]
    int   way = -1;                       // lane j: parent col on path

    while (freeRows) {
        const int f = (int)__builtin_ctz(freeRows);
        freeRows &= freeRows - 1;

        float minv  = INFV;
        bool  used  = !isCol;             // lanes>=24 permanently excluded
        bool  inTree = false;
        int   s_j0 = -1;                  // virtual column
        int   s_i0 = f;
        float s_u0 = readlane_f(uu, f);
        float cij  = ctcol[s_i0];         // head load for the first iteration
        int   j1   = 0;

        while (true) {
            inTree = inTree || (lane == s_i0);

            float cur = (cij - s_u0) - v;             // exact old association

            bool imp = (!used) && (cur < minv);
            minv = imp ? cur : minv;                  // used lanes frozen at INFV
            way  = imp ? s_j0 : way;

            // packed argmin via DPP: monotone uint key, low 6 bits = lane
            unsigned kmin = (unsigned)readlane_i(
                (int)wave_min32(packkey(minv, lane)), 31);
            j1 = (int)(kmin & 63u);

            // three INDEPENDENT readlanes off j1
            float delta = readlane_f(minv, j1);
            int   i0n   = readlane_i(p, j1);
            float u0n   = readlane_f(pu, j1);

            // issue next row's cost load NOW (clamped if i0n<0; result then
            // dead). Its ~120cy LDS latency overlaps the update block +
            // backedge instead of heading the next iteration's chain.
            float cijN = ctcol[(i0n < 0) ? 0 : i0n];

            // dual updates — predicated, same used/inTree sets as before
            uu   = inTree ? uu + delta : uu;
            v    = used   ? v - delta  : v;
            pu   = used   ? pu + delta : pu;          // mirrors u[p[j]]
            minv = used   ? minv       : minv - delta;

            // col j1 joins the used set for subsequent iterations
            bool sel = (lane == j1);
            minv = sel ? INFV : minv;
            used = used || sel;

            if (i0n < 0) break;                       // free column reached
            s_j0 = j1; s_i0 = i0n; s_u0 = u0n; cij = cijN;
        }

        // augment back to the virtual column; resync pu = u[p[j]] on the path
        int jcur = j1;
        while (true) {
            int   wj   = readlane_i(way, jcur);
            int   pnew = (wj < 0) ? f : readlane_i(p, wj);
            float pun  = readlane_f(uu, pnew);
            if (lane == jcur) { p = pnew; pu = pun; }
            if (wj < 0) break;
            jcur = wj;
        }
    }

    if (isCol) colw[wv][p] = lane;        // col_ind[row p] = col `lane`
    LGKM0();

    // ============ Phase C: gather out[i][:] = slots[col[i]][:] =============
    const float4* sg4 = (const float4*)(slots + (size_t)bw * N * D);
    float4*       og4 = (float4*)(out + (size_t)bw * N * D);
    #pragma unroll
    for (int i = 0; i < N; ++i) {
        int c = colw[wv][i];
        og4[i * 64 + lane] = sg4[c * 64 + lane];
    }
}

extern "C" void kernel_launch(void* const* d_in, const int* in_sizes, int n_in,
                              void* d_out, int out_size, void* d_ws, size_t ws_size,
                              hipStream_t stream) {
    const float* slots = (const float*)d_in[0];
    const float* prev  = (const float*)d_in[1];
    float* out = (float*)d_out;
    int B = in_sizes[0] / (N * D);
    int grid = (B + NB - 1) / NB;
    hungarian_fused<<<grid, BLK, 0, stream>>>(slots, prev, out, B);
}